// Round 2
// baseline (1375.429 us; speedup 1.0000x reference)
//
#include <hip/hip_runtime.h>
#include <math.h>

#define NROWS 16384
#define MINN 1e-15f

__device__ __forceinline__ float waveSum(float v) {
    #pragma unroll
    for (int m = 32; m >= 1; m >>= 1) v += __shfl_xor(v, m, 64);
    return v;
}

// Kernel 1: per row of x, compute ht = logmap0(proj(expmap0(logmap0(x) @ W^T)))
// One wave per row; W staged transposed in LDS (WT[d][k] = W[k][d]).
__global__ __launch_bounds__(256) void prep_kernel(
    const float* __restrict__ x, const float* __restrict__ W,
    float* __restrict__ ht)
{
    __shared__ float WT[64 * 64];
    for (int t = threadIdx.x; t < 64 * 64; t += 256) {
        int k = t >> 6, d = t & 63;
        WT[d * 64 + k] = W[t];   // broadcast reads later -> conflict-free
    }
    __syncthreads();
    const int lane = threadIdx.x & 63;
    const int row = blockIdx.x * 4 + (threadIdx.x >> 6);

    float xv = x[row * 64 + lane];
    // u = logmap0(x): u[0]=0, u[d] = acosh(max(x0,1+1e-7)) * x[d] / max(||x[1:]||, MINN)
    float sq = (lane == 0) ? 0.f : xv * xv;
    float yn = fmaxf(sqrtf(waveSum(sq)), MINN);
    float theta = fmaxf(__shfl(xv, 0, 64), 1.0f + 1e-7f);
    float s = acoshf(theta) / yn;
    float u = (lane == 0) ? 0.f : s * xv;

    // h1[k] = sum_d u[d] * W[k][d]  (lane = k); u[0]==0 so start at d=1
    float h1 = 0.f;
    #pragma unroll
    for (int d = 1; d < 64; ++d)
        h1 = fmaf(__shfl(u, d, 64), WT[d * 64 + lane], h1);

    // ht = logmap0(proj(expmap0(h1)))  (expmap0/proj discard component 0)
    float z = (lane == 0) ? 0.f : h1;
    float zn = fmaxf(sqrtf(waveSum(z * z)), MINN);
    float sh = sinhf(zn);
    float ey = sh * z / zn;                       // lane0 -> 0
    float s2 = waveSum(ey * ey);
    float first = sqrtf(fmaxf(1.f + s2, MINN));   // proj first component
    float ynb = fmaxf(sqrtf(s2), MINN);
    float th2 = fmaxf(first, 1.0f + 1e-7f);
    float coef = acoshf(th2) / ynb;
    float htv = (lane == 0) ? 0.f : coef * ey;
    ht[row * 64 + lane] = htv;
}

// Kernel 2: h2 = adj @ ht (sparse-aware stream), fused epilogue:
// out = proj(expmap0(mask*relu(logmap0(proj(expmap0(h2))))))
// One wave per output row. Lane d accumulates column d of the result.
__global__ __launch_bounds__(256) void agg_kernel(
    const float* __restrict__ adj, const float* __restrict__ ht,
    float* __restrict__ out)
{
    const int lane = threadIdx.x & 63;
    const int row = blockIdx.x * 4 + (threadIdx.x >> 6);
    const float* arow = adj + (size_t)row * NROWS;

    float acc = 0.f;
    // 256 columns per iteration: lane L covers cols [it*256 + L*4, +4)
    for (int it = 0; it < NROWS / 256; ++it) {
        const float4 v = *(const float4*)(arow + it * 256 + lane * 4);
        unsigned int any = __float_as_uint(v.x) | __float_as_uint(v.y) |
                           __float_as_uint(v.z) | __float_as_uint(v.w);
        unsigned long long mask = __ballot(any != 0u);   // masked entries are exact +0.0
        while (mask) {
            int L = __ffsll((long long)mask) - 1;
            mask &= mask - 1;
            float a0 = __shfl(v.x, L, 64);
            float a1 = __shfl(v.y, L, 64);
            float a2 = __shfl(v.z, L, 64);
            float a3 = __shfl(v.w, L, 64);
            int jbase = it * 256 + L * 4;
            if (a0 != 0.f) acc = fmaf(a0, ht[(size_t)(jbase + 0) * 64 + lane], acc);
            if (a1 != 0.f) acc = fmaf(a1, ht[(size_t)(jbase + 1) * 64 + lane], acc);
            if (a2 != 0.f) acc = fmaf(a2, ht[(size_t)(jbase + 2) * 64 + lane], acc);
            if (a3 != 0.f) acc = fmaf(a3, ht[(size_t)(jbase + 3) * 64 + lane], acc);
        }
    }

    // Epilogue (literal reference clamps; empty rows -> [1,0,...,0])
    float z = (lane == 0) ? 0.f : acc;             // adj@ht has zero first column
    float zn = fmaxf(sqrtf(waveSum(z * z)), MINN);
    float sh = sinhf(zn);
    float ey = sh * z / zn;                        // expmap0 tangent part
    float s2 = waveSum(ey * ey);
    float first = sqrtf(fmaxf(1.f + s2, MINN));    // proj first component
    float ynb = fmaxf(sqrtf(s2), MINN);
    float th2 = fmaxf(first, 1.0f + 1e-7f);
    float l = acoshf(th2) / ynb * ey;              // logmap0 tangent (lane0 -> 0)
    float xt = fmaxf(l, 0.f);                      // relu
    if (lane == 0) xt = 0.f;                       // mask zeroes component 0
    float xn = fmaxf(sqrtf(waveSum(xt * xt)), MINN);
    float sh2 = sinhf(xn);
    float oy = sh2 * xt / xn;
    float o0 = sqrtf(fmaxf(1.f + waveSum(oy * oy), MINN));  // proj first comp
    float outv = (lane == 0) ? o0 : oy;
    out[row * 64 + lane] = outv;
}

extern "C" void kernel_launch(void* const* d_in, const int* in_sizes, int n_in,
                              void* d_out, int out_size, void* d_ws, size_t ws_size,
                              hipStream_t stream) {
    const float* x   = (const float*)d_in[0];
    const float* adj = (const float*)d_in[1];
    const float* W   = (const float*)d_in[2];
    float* out = (float*)d_out;
    float* ht  = (float*)d_ws;   // 16384*64*4 = 4 MiB scratch

    prep_kernel<<<NROWS / 4, 256, 0, stream>>>(x, W, ht);
    agg_kernel<<<NROWS / 4, 256, 0, stream>>>(adj, ht, out);
}

// Round 3
// 1342.248 us; speedup vs baseline: 1.0247x; 1.0247x over previous
//
#include <hip/hip_runtime.h>
#include <math.h>

#define NROWS 16384
#define MINN 1e-15f

typedef float vf4 __attribute__((ext_vector_type(4)));

__device__ __forceinline__ float waveSum(float v) {
    #pragma unroll
    for (int m = 32; m >= 1; m >>= 1) v += __shfl_xor(v, m, 64);
    return v;
}

// Kernel 1: per row of x, compute ht = logmap0(proj(expmap0(logmap0(x) @ W^T)))
// One wave per row; W staged transposed in LDS (WT[d][k] = W[k][d]).
__global__ __launch_bounds__(256) void prep_kernel(
    const float* __restrict__ x, const float* __restrict__ W,
    float* __restrict__ ht)
{
    __shared__ float WT[64 * 64];
    for (int t = threadIdx.x; t < 64 * 64; t += 256) {
        int k = t >> 6, d = t & 63;
        WT[d * 64 + k] = W[t];   // broadcast reads later -> conflict-free
    }
    __syncthreads();
    const int lane = threadIdx.x & 63;
    const int row = blockIdx.x * 4 + (threadIdx.x >> 6);

    float xv = x[row * 64 + lane];
    // u = logmap0(x)
    float sq = (lane == 0) ? 0.f : xv * xv;
    float yn = fmaxf(sqrtf(waveSum(sq)), MINN);
    float theta = fmaxf(__shfl(xv, 0, 64), 1.0f + 1e-7f);
    float s = acoshf(theta) / yn;
    float u = (lane == 0) ? 0.f : s * xv;

    // h1[k] = sum_d u[d] * W[k][d]  (lane = k); u[0]==0 so start at d=1
    float h1 = 0.f;
    #pragma unroll
    for (int d = 1; d < 64; ++d)
        h1 = fmaf(__shfl(u, d, 64), WT[d * 64 + lane], h1);

    // ht = logmap0(proj(expmap0(h1)))
    float z = (lane == 0) ? 0.f : h1;
    float zn = fmaxf(sqrtf(waveSum(z * z)), MINN);
    float sh = sinhf(zn);
    float ey = sh * z / zn;                       // lane0 -> 0
    float s2 = waveSum(ey * ey);
    float first = sqrtf(fmaxf(1.f + s2, MINN));
    float ynb = fmaxf(sqrtf(s2), MINN);
    float th2 = fmaxf(first, 1.0f + 1e-7f);
    float coef = acoshf(th2) / ynb;
    float htv = (lane == 0) ? 0.f : coef * ey;
    ht[row * 64 + lane] = htv;
}

// Kernel 2: h2 = adj @ ht (sparse-aware stream) + fused epilogue.
// One wave per output row; 4 independent 1KiB loads in flight per body iter.
__global__ __launch_bounds__(256) void agg_kernel(
    const float* __restrict__ adj, const float* __restrict__ ht,
    float* __restrict__ out)
{
    const int lane = threadIdx.x & 63;
    const int row = blockIdx.x * 4 + (threadIdx.x >> 6);
    const float* arow = adj + (size_t)row * NROWS;

    float acc = 0.f;
    // Body iter covers 1024 cols as 4 windows of 256; loads issued together.
    for (int it = 0; it < NROWS / 1024; ++it) {
        const float* base = arow + it * 1024 + lane * 4;
        vf4 v0 = __builtin_nontemporal_load((const vf4*)(base + 0));
        vf4 v1 = __builtin_nontemporal_load((const vf4*)(base + 256));
        vf4 v2 = __builtin_nontemporal_load((const vf4*)(base + 512));
        vf4 v3 = __builtin_nontemporal_load((const vf4*)(base + 768));
        #pragma unroll
        for (int w = 0; w < 4; ++w) {
            vf4 v = (w == 0) ? v0 : (w == 1) ? v1 : (w == 2) ? v2 : v3;
            unsigned int any = __float_as_uint(v.x) | __float_as_uint(v.y) |
                               __float_as_uint(v.z) | __float_as_uint(v.w);
            unsigned long long mask = __ballot(any != 0u);  // zeros are exact +0.0
            int jwin = it * 1024 + w * 256;
            while (mask) {
                int L = __ffsll((long long)mask) - 1;
                mask &= mask - 1;
                float a0 = __shfl(v.x, L, 64);
                float a1 = __shfl(v.y, L, 64);
                float a2 = __shfl(v.z, L, 64);
                float a3 = __shfl(v.w, L, 64);
                int jbase = jwin + L * 4;
                if (a0 != 0.f) acc = fmaf(a0, ht[(size_t)(jbase + 0) * 64 + lane], acc);
                if (a1 != 0.f) acc = fmaf(a1, ht[(size_t)(jbase + 1) * 64 + lane], acc);
                if (a2 != 0.f) acc = fmaf(a2, ht[(size_t)(jbase + 2) * 64 + lane], acc);
                if (a3 != 0.f) acc = fmaf(a3, ht[(size_t)(jbase + 3) * 64 + lane], acc);
            }
        }
    }

    // Epilogue (literal reference clamps; empty rows -> [1,0,...,0])
    float z = (lane == 0) ? 0.f : acc;
    float zn = fmaxf(sqrtf(waveSum(z * z)), MINN);
    float sh = sinhf(zn);
    float ey = sh * z / zn;
    float s2 = waveSum(ey * ey);
    float first = sqrtf(fmaxf(1.f + s2, MINN));
    float ynb = fmaxf(sqrtf(s2), MINN);
    float th2 = fmaxf(first, 1.0f + 1e-7f);
    float l = acoshf(th2) / ynb * ey;
    float xt = fmaxf(l, 0.f);
    if (lane == 0) xt = 0.f;
    float xn = fmaxf(sqrtf(waveSum(xt * xt)), MINN);
    float sh2 = sinhf(xn);
    float oy = sh2 * xt / xn;
    float o0 = sqrtf(fmaxf(1.f + waveSum(oy * oy), MINN));
    float outv = (lane == 0) ? o0 : oy;
    out[row * 64 + lane] = outv;
}

extern "C" void kernel_launch(void* const* d_in, const int* in_sizes, int n_in,
                              void* d_out, int out_size, void* d_ws, size_t ws_size,
                              hipStream_t stream) {
    const float* x   = (const float*)d_in[0];
    const float* adj = (const float*)d_in[1];
    const float* W   = (const float*)d_in[2];
    float* out = (float*)d_out;
    float* ht  = (float*)d_ws;   // 16384*64*4 = 4 MiB scratch

    prep_kernel<<<NROWS / 4, 256, 0, stream>>>(x, W, ht);
    agg_kernel<<<NROWS / 4, 256, 0, stream>>>(adj, ht, out);
}